// Round 3
// baseline (2468.612 us; speedup 1.0000x reference)
//
#include <hip/hip_runtime.h>

#define BATCH   16
#define NPTS    8192
#define NCH     64
#define NPOINT  1024
#define NSAMPLE 32
#define R2      0.01f
#define NWORK   240
#define NGROUPS 2048   // BATCH * (NPOINT/8)

__device__ inline unsigned long long shfl_xor_u64(unsigned long long x, int m) {
    int lo = (int)(unsigned)(x & 0xffffffffull);
    int hi = (int)(unsigned)(x >> 32);
    lo = __shfl_xor(lo, m, 64);
    hi = __shfl_xor(hi, m, 64);
    return ((unsigned long long)(unsigned)hi << 32) | (unsigned)lo;
}

struct FpsShared {
    float pts[NPTS * 3];                    // 96 KB
    unsigned long long red[2][4];
};
struct WkShared {
    float tile[64][65];                     // transpose staging
    float w1[64 * 68];                      // W1 padded rows (col 67 = 0)
    float w2[64 * 64];
    float w3[128 * 64];
    float b1s[64], b2s[64], b3s[128];
    int   gidx[8][NSAMPLE];
};

__global__ void init_kernel(int* prog, int* cnt) {
    if (threadIdx.x < BATCH) prog[threadIdx.x] = 0;
    if (threadIdx.x == BATCH) *cnt = 0;
}

__global__ __launch_bounds__(256, 1) void fused_kernel(const float* __restrict__ xyz,
                                                       const float* __restrict__ feat,
                                                       const float* __restrict__ W1,
                                                       const float* __restrict__ b1,
                                                       const float* __restrict__ W2,
                                                       const float* __restrict__ b2,
                                                       const float* __restrict__ W3,
                                                       const float* __restrict__ b3,
                                                       float* __restrict__ new_xyz,
                                                       float* __restrict__ out_feat,
                                                       float* __restrict__ feat_t,
                                                       int* prog, int* cnt) {
    __shared__ union { FpsShared fps; WkShared wk; } U;
    const int t = threadIdx.x;

    if (blockIdx.x < BATCH) {
        // ================= FPS (verified-exact) =================
        const int b = blockIdx.x;
        const float* g = xyz + (size_t)b * NPTS * 3;
        for (int i = t; i < NPTS * 3; i += 256) U.fps.pts[i] = g[i];
        __syncthreads();

        float px[32], py[32], pz[32], dist[32];
#pragma unroll
        for (int k = 0; k < 32; ++k) {
            const int p = t + (k << 8);
            px[k] = U.fps.pts[3 * p + 0];
            py[k] = U.fps.pts[3 * p + 1];
            pz[k] = U.fps.pts[3 * p + 2];
            dist[k] = 1e10f;
        }

        float fx = U.fps.pts[0], fy = U.fps.pts[1], fz = U.fps.pts[2];
        const int wave = t >> 6;

        for (int it = 0; it < NPOINT; ++it) {
            if (t == 0) {
                float* nx = new_xyz + ((size_t)b * NPOINT + it) * 3;
                nx[0] = fx; nx[1] = fy; nx[2] = fz;
                if (((it + 1) & 15) == 0)
                    __hip_atomic_store(&prog[b], it + 1, __ATOMIC_RELEASE,
                                       __HIP_MEMORY_SCOPE_AGENT);
            }
            float bestv = -1.0f; int bestk = 0;
#pragma unroll
            for (int k = 0; k < 32; ++k) {
                float dx = __fsub_rn(px[k], fx);
                float dy = __fsub_rn(py[k], fy);
                float dz = __fsub_rn(pz[k], fz);
                float d  = __fadd_rn(__fadd_rn(__fmul_rn(dx, dx), __fmul_rn(dy, dy)),
                                     __fmul_rn(dz, dz));
                float nd = fminf(dist[k], d);
                dist[k] = nd;
                if (nd > bestv) { bestv = nd; bestk = k; }
            }
            const int besti = t + (bestk << 8);
            unsigned long long key =
                ((unsigned long long)__float_as_uint(bestv) << 32) | (unsigned)(~besti);
#pragma unroll
            for (int m = 1; m < 64; m <<= 1) {
                unsigned long long o = shfl_xor_u64(key, m);
                if (o > key) key = o;
            }
            const int par = it & 1;
            if ((t & 63) == 0) U.fps.red[par][wave] = key;
            __syncthreads();
            unsigned long long kk = U.fps.red[par][0];
            unsigned long long k1 = U.fps.red[par][1];
            unsigned long long k2 = U.fps.red[par][2];
            unsigned long long k3 = U.fps.red[par][3];
            if (k1 > kk) kk = k1;
            if (k2 > kk) kk = k2;
            if (k3 > kk) kk = k3;
            const int far = (int)(~(unsigned)kk);
            fx = U.fps.pts[3 * far + 0];
            fy = U.fps.pts[3 * far + 1];
            fz = U.fps.pts[3 * far + 2];
        }
        // final publish (iteration 1023 -> prog=1024 covered by the &15 rule)
        return;
    }

    // ================= workers =================
    const int wid = blockIdx.x - BATCH;

    // Phase 1: transpose (B,C,N) -> (B,N,C)
    for (int tid = wid; tid < BATCH * (NPTS / 64); tid += NWORK) {
        const int b  = tid >> 7;
        const int n0 = (tid & 127) << 6;
        const int i  = t & 63, c0 = t >> 6;
        const float* src = feat + (size_t)b * NCH * NPTS;
#pragma unroll
        for (int r = 0; r < 16; ++r) {
            int c = c0 + r * 4;
            U.wk.tile[c][i] = src[(size_t)c * NPTS + n0 + i];
        }
        __syncthreads();
        const int cc = t & 63, i0 = t >> 6;
        float* dst = feat_t + ((size_t)b * NPTS + n0) * NCH;
#pragma unroll
        for (int r = 0; r < 16; ++r) {
            int ii = i0 + r * 4;
            dst[(size_t)ii * NCH + cc] = U.wk.tile[cc][ii];
        }
        __syncthreads();
    }
    if (t == 0)
        __hip_atomic_fetch_add(cnt, 1, __ATOMIC_ACQ_REL, __HIP_MEMORY_SCOPE_AGENT);

    // Phase 2: stage all weights once
    for (int i = t; i < 64 * 67; i += 256) U.wk.w1[(i / 67) * 68 + (i % 67)] = W1[i];
    if (t < 64) { U.wk.w1[t * 68 + 67] = 0.0f; U.wk.b1s[t] = b1[t]; U.wk.b2s[t] = b2[t]; }
    if (t < 128) U.wk.b3s[t] = b3[t];
    for (int i = t; i < 64 * 64; i += 256) U.wk.w2[i] = W2[i];
    for (int i = t; i < 128 * 64; i += 256) U.wk.w3[i] = W3[i];

    // wait for all workers' transpose (feat_t fully written & visible)
    if (t == 0) {
        while (__hip_atomic_load(cnt, __ATOMIC_ACQUIRE, __HIP_MEMORY_SCOPE_AGENT) < NWORK)
            __builtin_amdgcn_s_sleep(8);
    }
    __syncthreads();

    // Phase 3: per-group BQ + MLP
    const int wv = t >> 6, lane = t & 63;
    for (int gidx_g = wid; gidx_g < NGROUPS; gidx_g += NWORK) {
        const int b  = gidx_g >> 7;
        const int p0 = (gidx_g & 127) << 3;
        if (t == 0) {
            while (__hip_atomic_load(&prog[b], __ATOMIC_ACQUIRE,
                                     __HIP_MEMORY_SCOPE_AGENT) < p0 + 8)
                __builtin_amdgcn_s_sleep(8);
        }
        __syncthreads();

        // ---- ball query: wave wv handles local centers 2wv, 2wv+1 ----
        const float* pts = xyz + (size_t)b * NPTS * 3;
        for (int q = 0; q < 2; ++q) {
            const int ci = wv * 2 + q;
            const float* nx = new_xyz + ((size_t)b * NPOINT + p0 + ci) * 3;
            const float cx = nx[0], cy = nx[1], cz = nx[2];
            int hits = 0, first = 0;
            for (int j0 = 0; j0 < NPTS; j0 += 64) {
                const int j = j0 + lane;
                float x = pts[3 * j], y = pts[3 * j + 1], z = pts[3 * j + 2];
                float dx = __fsub_rn(x, cx), dy = __fsub_rn(y, cy), dz = __fsub_rn(z, cz);
                float d2 = __fadd_rn(__fadd_rn(__fmul_rn(dx, dx), __fmul_rn(dy, dy)),
                                     __fmul_rn(dz, dz));
                const bool pred = d2 < R2;
                const unsigned long long mask = __ballot(pred);
                if (hits == 0 && mask)
                    first = j0 + (int)(__ffsll((unsigned long long)mask) - 1);
                if (pred) {
                    int slot = hits + (int)__popcll(mask & ((1ull << lane) - 1ull));
                    if (slot < NSAMPLE) U.wk.gidx[ci][slot] = j;
                }
                hits += (int)__popcll(mask);
                if (hits >= NSAMPLE) break;
            }
            if (hits < NSAMPLE && lane >= hits && lane < NSAMPLE)
                U.wk.gidx[ci][lane] = first;
        }
        __syncthreads();

        // ---- MLP: 32 threads per center ----
        const int ci = t >> 5, s = t & 31;
        const int p  = p0 + ci;
        const int gi = U.wk.gidx[ci][s];
        const float* nx = new_xyz + ((size_t)b * NPOINT + p) * 3;
        const float* pp = xyz + ((size_t)b * NPTS + gi) * 3;
        float h[68];
        h[0] = pp[0] - nx[0];
        h[1] = pp[1] - nx[1];
        h[2] = pp[2] - nx[2];
        const float4* fp = (const float4*)(feat_t + ((size_t)b * NPTS + gi) * NCH);
#pragma unroll
        for (int qq = 0; qq < 16; ++qq) {
            float4 v = fp[qq];
            h[3 + 4 * qq] = v.x; h[4 + 4 * qq] = v.y;
            h[5 + 4 * qq] = v.z; h[6 + 4 * qq] = v.w;
        }
        h[67] = 0.0f;

        float h1[64];
#pragma unroll
        for (int o = 0; o < 64; ++o) {
            const float4* wr = (const float4*)(&U.wk.w1[o * 68]);
            float a0 = 0.f, a1 = 0.f, a2 = 0.f, a3 = 0.f;
#pragma unroll
            for (int qq = 0; qq < 17; ++qq) {
                float4 w = wr[qq];
                a0 = fmaf(w.x, h[4 * qq + 0], a0);
                a1 = fmaf(w.y, h[4 * qq + 1], a1);
                a2 = fmaf(w.z, h[4 * qq + 2], a2);
                a3 = fmaf(w.w, h[4 * qq + 3], a3);
            }
            h1[o] = fmaxf((a0 + a1) + (a2 + a3) + U.wk.b1s[o], 0.0f);
        }

        float h2[64];
#pragma unroll
        for (int o = 0; o < 64; ++o) {
            const float4* wr = (const float4*)(&U.wk.w2[o * 64]);
            float a0 = 0.f, a1 = 0.f, a2 = 0.f, a3 = 0.f;
#pragma unroll
            for (int qq = 0; qq < 16; ++qq) {
                float4 w = wr[qq];
                a0 = fmaf(w.x, h1[4 * qq + 0], a0);
                a1 = fmaf(w.y, h1[4 * qq + 1], a1);
                a2 = fmaf(w.z, h1[4 * qq + 2], a2);
                a3 = fmaf(w.w, h1[4 * qq + 3], a3);
            }
            h2[o] = fmaxf((a0 + a1) + (a2 + a3) + U.wk.b2s[o], 0.0f);
        }

        float* outp = out_feat + ((size_t)b * 128) * NPOINT + p;
#pragma unroll
        for (int o = 0; o < 128; ++o) {
            const float4* wr = (const float4*)(&U.wk.w3[o * 64]);
            float a0 = 0.f, a1 = 0.f, a2 = 0.f, a3 = 0.f;
#pragma unroll
            for (int qq = 0; qq < 16; ++qq) {
                float4 w = wr[qq];
                a0 = fmaf(w.x, h2[4 * qq + 0], a0);
                a1 = fmaf(w.y, h2[4 * qq + 1], a1);
                a2 = fmaf(w.z, h2[4 * qq + 2], a2);
                a3 = fmaf(w.w, h2[4 * qq + 3], a3);
            }
            float acc = fmaxf((a0 + a1) + (a2 + a3) + U.wk.b3s[o], 0.0f);
#pragma unroll
            for (int m = 1; m < 32; m <<= 1) acc = fmaxf(acc, __shfl_xor(acc, m, 64));
            if (s == 0) outp[(size_t)o * NPOINT] = acc;
        }
    }
}

extern "C" void kernel_launch(void* const* d_in, const int* in_sizes, int n_in,
                              void* d_out, int out_size, void* d_ws, size_t ws_size,
                              hipStream_t stream) {
    const float* xyz  = (const float*)d_in[0];
    const float* feat = (const float*)d_in[1];
    const float* W1   = (const float*)d_in[2];
    const float* b1   = (const float*)d_in[3];
    const float* W2   = (const float*)d_in[4];
    const float* b2   = (const float*)d_in[5];
    const float* W3   = (const float*)d_in[6];
    const float* b3   = (const float*)d_in[7];

    float* new_xyz  = (float*)d_out;                                  // (B, NPOINT, 3)
    float* out_feat = (float*)d_out + (size_t)BATCH * NPOINT * 3;     // (B, 128, NPOINT)

    int*   prog   = (int*)d_ws;                                       // [16]
    int*   cnt    = prog + BATCH;                                     // [1]
    float* feat_t = (float*)((char*)d_ws + 256);                      // (B, NPTS, NCH)

    hipLaunchKernelGGL(init_kernel, dim3(1), dim3(64), 0, stream, prog, cnt);
    hipLaunchKernelGGL(fused_kernel, dim3(BATCH + NWORK), dim3(256), 0, stream,
                       xyz, feat, W1, b1, W2, b2, W3, b3,
                       new_xyz, out_feat, feat_t, prog, cnt);
}

// Round 4
// 2296.185 us; speedup vs baseline: 1.0751x; 1.0751x over previous
//
#include <hip/hip_runtime.h>

#define BATCH   16
#define NPTS    8192
#define NCH     64
#define NPOINT  1024
#define NSAMPLE 32
#define R2      0.01f
#define NWORK   240
#define NGROUPS 2048   // BATCH * (NPOINT/8)

__device__ inline unsigned long long shfl_xor_u64(unsigned long long x, int m) {
    int lo = (int)(unsigned)(x & 0xffffffffull);
    int hi = (int)(unsigned)(x >> 32);
    lo = __shfl_xor(lo, m, 64);
    hi = __shfl_xor(hi, m, 64);
    return ((unsigned long long)(unsigned)hi << 32) | (unsigned)lo;
}

struct FpsShared {
    float pts[NPTS * 3];                    // 96 KB
    unsigned long long red[2][4];
};
struct WkShared {
    float tile[64][65];                     // transpose staging
    int   cidx[8];
    float cxyz[8][3];
    int   gidx[8][NSAMPLE];
};

__global__ __launch_bounds__(256) void init_kernel(int* fps_idx, int* cnt) {
    const int i = blockIdx.x * 256 + threadIdx.x;
    if (i < BATCH * NPOINT) fps_idx[i] = -1;
    if (i == 0) *cnt = 0;
}

__global__ __launch_bounds__(256, 1) void fused_kernel(const float* __restrict__ xyz,
                                                       const float* __restrict__ feat,
                                                       const float* __restrict__ W1,
                                                       const float* __restrict__ b1,
                                                       const float* __restrict__ W2,
                                                       const float* __restrict__ b2,
                                                       const float* __restrict__ W3,
                                                       const float* __restrict__ b3,
                                                       float* __restrict__ new_xyz,
                                                       float* __restrict__ out_feat,
                                                       float* __restrict__ feat_t,
                                                       int* fps_idx, int* cnt) {
    __shared__ union { FpsShared fps; WkShared wk; } U;
    const int t = threadIdx.x;

    if (blockIdx.x < BATCH) {
        // ================= FPS (verified-exact arithmetic) =================
        const int b = blockIdx.x;
        const float* g = xyz + (size_t)b * NPTS * 3;
        for (int i = t; i < NPTS * 3; i += 256) U.fps.pts[i] = g[i];
        __syncthreads();

        float px[32], py[32], pz[32], dist[32];
#pragma unroll
        for (int k = 0; k < 32; ++k) {
            const int p = t + (k << 8);
            px[k] = U.fps.pts[3 * p + 0];
            py[k] = U.fps.pts[3 * p + 1];
            pz[k] = U.fps.pts[3 * p + 2];
            dist[k] = 1e10f;
        }

        float fx = U.fps.pts[0], fy = U.fps.pts[1], fz = U.fps.pts[2];
        const int wave = t >> 6;
        int cur = 0;   // index of the point whose coords are (fx,fy,fz)

        for (int it = 0; it < NPOINT; ++it) {
            if (t == 0) {
                float* nx = new_xyz + ((size_t)b * NPOINT + it) * 3;
                nx[0] = fx; nx[1] = fy; nx[2] = fz;
                __hip_atomic_store(&fps_idx[b * NPOINT + it], cur,
                                   __ATOMIC_RELAXED, __HIP_MEMORY_SCOPE_AGENT);
            }
            float bestv = -1.0f; int bestk = 0;
#pragma unroll
            for (int k = 0; k < 32; ++k) {
                float dx = __fsub_rn(px[k], fx);
                float dy = __fsub_rn(py[k], fy);
                float dz = __fsub_rn(pz[k], fz);
                float d  = __fadd_rn(__fadd_rn(__fmul_rn(dx, dx), __fmul_rn(dy, dy)),
                                     __fmul_rn(dz, dz));
                float nd = fminf(dist[k], d);
                dist[k] = nd;
                if (nd > bestv) { bestv = nd; bestk = k; }
            }
            const int besti = t + (bestk << 8);
            unsigned long long key =
                ((unsigned long long)__float_as_uint(bestv) << 32) | (unsigned)(~besti);
#pragma unroll
            for (int m = 1; m < 64; m <<= 1) {
                unsigned long long o = shfl_xor_u64(key, m);
                if (o > key) key = o;
            }
            const int par = it & 1;
            if ((t & 63) == 0) U.fps.red[par][wave] = key;
            __syncthreads();
            unsigned long long kk = U.fps.red[par][0];
            unsigned long long k1 = U.fps.red[par][1];
            unsigned long long k2 = U.fps.red[par][2];
            unsigned long long k3 = U.fps.red[par][3];
            if (k1 > kk) kk = k1;
            if (k2 > kk) kk = k2;
            if (k3 > kk) kk = k3;
            const int far = (int)(~(unsigned)kk);
            cur = far;
            fx = U.fps.pts[3 * far + 0];
            fy = U.fps.pts[3 * far + 1];
            fz = U.fps.pts[3 * far + 2];
        }
        return;
    }

    // ================= workers =================
    const int wid = blockIdx.x - BATCH;

    // Phase 1: transpose (B,C,N) -> (B,N,C)
    for (int tid = wid; tid < BATCH * (NPTS / 64); tid += NWORK) {
        const int b  = tid >> 7;
        const int n0 = (tid & 127) << 6;
        const int i  = t & 63, c0 = t >> 6;
        const float* src = feat + (size_t)b * NCH * NPTS;
#pragma unroll
        for (int r = 0; r < 16; ++r) {
            int c = c0 + r * 4;
            U.wk.tile[c][i] = src[(size_t)c * NPTS + n0 + i];
        }
        __syncthreads();
        const int cc = t & 63, i0 = t >> 6;
        float* dst = feat_t + ((size_t)b * NPTS + n0) * NCH;
#pragma unroll
        for (int r = 0; r < 16; ++r) {
            int ii = i0 + r * 4;
            dst[(size_t)ii * NCH + cc] = U.wk.tile[cc][ii];
        }
        __syncthreads();
    }
    // one-time barrier: release our feat_t writes, then a single acquire
    if (t == 0) {
        __hip_atomic_fetch_add(cnt, 1, __ATOMIC_ACQ_REL, __HIP_MEMORY_SCOPE_AGENT);
        while (__hip_atomic_load(cnt, __ATOMIC_RELAXED, __HIP_MEMORY_SCOPE_AGENT) < NWORK)
            __builtin_amdgcn_s_sleep(8);
        (void)__hip_atomic_load(cnt, __ATOMIC_ACQUIRE, __HIP_MEMORY_SCOPE_AGENT);
    }
    __syncthreads();

    // Phase 2: groups ordered by required FPS progress, spread across batches.
    const int wv = t >> 6, lane = t & 63;
    for (int ord = wid; ord < NGROUPS; ord += NWORK) {
        const int b  = ord & 15;
        const int p0 = (ord >> 4) << 3;

        // lane-parallel sentinel spin on the 8 center indices (relaxed: no inv)
        if (t < 8) {
            const int* ip = fps_idx + b * NPOINT + p0 + t;
            int gi;
            while ((gi = __hip_atomic_load(ip, __ATOMIC_RELAXED,
                                           __HIP_MEMORY_SCOPE_AGENT)) < 0)
                __builtin_amdgcn_s_sleep(8);
            U.wk.cidx[t] = gi;
            const float* c = xyz + ((size_t)b * NPTS + gi) * 3;
            U.wk.cxyz[t][0] = c[0];
            U.wk.cxyz[t][1] = c[1];
            U.wk.cxyz[t][2] = c[2];
        }
        __syncthreads();

        // ---- ball query: wave wv handles local centers 2wv, 2wv+1 ----
        const float* pts = xyz + (size_t)b * NPTS * 3;
        for (int q = 0; q < 2; ++q) {
            const int ci = wv * 2 + q;
            const float cx = U.wk.cxyz[ci][0];
            const float cy = U.wk.cxyz[ci][1];
            const float cz = U.wk.cxyz[ci][2];
            int hits = 0, first = 0;
            for (int j0 = 0; j0 < NPTS; j0 += 64) {
                const int j = j0 + lane;
                float x = pts[3 * j], y = pts[3 * j + 1], z = pts[3 * j + 2];
                float dx = __fsub_rn(x, cx), dy = __fsub_rn(y, cy), dz = __fsub_rn(z, cz);
                float d2 = __fadd_rn(__fadd_rn(__fmul_rn(dx, dx), __fmul_rn(dy, dy)),
                                     __fmul_rn(dz, dz));
                const bool pred = d2 < R2;
                const unsigned long long mask = __ballot(pred);
                if (hits == 0 && mask)
                    first = j0 + (int)(__ffsll((unsigned long long)mask) - 1);
                if (pred) {
                    int slot = hits + (int)__popcll(mask & ((1ull << lane) - 1ull));
                    if (slot < NSAMPLE) U.wk.gidx[ci][slot] = j;
                }
                hits += (int)__popcll(mask);
                if (hits >= NSAMPLE) break;
            }
            if (hits < NSAMPLE && lane >= hits && lane < NSAMPLE)
                U.wk.gidx[ci][lane] = first;
        }
        __syncthreads();

        // ---- MLP: 32 threads per center; weights via wave-uniform loads ----
        const int ci = t >> 5, s = t & 31;
        const int p  = p0 + ci;
        const int gi = U.wk.gidx[ci][s];
        const float nx0 = U.wk.cxyz[ci][0];
        const float nx1 = U.wk.cxyz[ci][1];
        const float nx2 = U.wk.cxyz[ci][2];
        const float* pp = xyz + ((size_t)b * NPTS + gi) * 3;
        float h[67];
        h[0] = pp[0] - nx0;
        h[1] = pp[1] - nx1;
        h[2] = pp[2] - nx2;
        const float4* fp = (const float4*)(feat_t + ((size_t)b * NPTS + gi) * NCH);
#pragma unroll
        for (int qq = 0; qq < 16; ++qq) {
            float4 v = fp[qq];
            h[3 + 4 * qq] = v.x; h[4 + 4 * qq] = v.y;
            h[5 + 4 * qq] = v.z; h[6 + 4 * qq] = v.w;
        }

        float h1[64];
#pragma unroll
        for (int o = 0; o < 64; ++o) {
            const float* wr = W1 + o * 67;
            float a0 = 0.f, a1 = 0.f, a2 = 0.f, a3 = 0.f;
#pragma unroll
            for (int qq = 0; qq < 16; ++qq) {
                a0 = fmaf(wr[4 * qq + 0], h[4 * qq + 0], a0);
                a1 = fmaf(wr[4 * qq + 1], h[4 * qq + 1], a1);
                a2 = fmaf(wr[4 * qq + 2], h[4 * qq + 2], a2);
                a3 = fmaf(wr[4 * qq + 3], h[4 * qq + 3], a3);
            }
            a0 = fmaf(wr[64], h[64], a0);
            a1 = fmaf(wr[65], h[65], a1);
            a2 = fmaf(wr[66], h[66], a2);
            h1[o] = fmaxf((a0 + a1) + (a2 + a3) + b1[o], 0.0f);
        }

        float h2[64];
#pragma unroll
        for (int o = 0; o < 64; ++o) {
            const float* wr = W2 + o * 64;
            float a0 = 0.f, a1 = 0.f, a2 = 0.f, a3 = 0.f;
#pragma unroll
            for (int qq = 0; qq < 16; ++qq) {
                a0 = fmaf(wr[4 * qq + 0], h1[4 * qq + 0], a0);
                a1 = fmaf(wr[4 * qq + 1], h1[4 * qq + 1], a1);
                a2 = fmaf(wr[4 * qq + 2], h1[4 * qq + 2], a2);
                a3 = fmaf(wr[4 * qq + 3], h1[4 * qq + 3], a3);
            }
            h2[o] = fmaxf((a0 + a1) + (a2 + a3) + b2[o], 0.0f);
        }

        float* outp = out_feat + ((size_t)b * 128) * NPOINT + p;
#pragma unroll
        for (int o = 0; o < 128; ++o) {
            const float* wr = W3 + o * 64;
            float a0 = 0.f, a1 = 0.f, a2 = 0.f, a3 = 0.f;
#pragma unroll
            for (int qq = 0; qq < 16; ++qq) {
                a0 = fmaf(wr[4 * qq + 0], h2[4 * qq + 0], a0);
                a1 = fmaf(wr[4 * qq + 1], h2[4 * qq + 1], a1);
                a2 = fmaf(wr[4 * qq + 2], h2[4 * qq + 2], a2);
                a3 = fmaf(wr[4 * qq + 3], h2[4 * qq + 3], a3);
            }
            float acc = fmaxf((a0 + a1) + (a2 + a3) + b3[o], 0.0f);
#pragma unroll
            for (int m = 1; m < 32; m <<= 1) acc = fmaxf(acc, __shfl_xor(acc, m, 64));
            if (s == 0) outp[(size_t)o * NPOINT] = acc;
        }
        __syncthreads();   // protect LDS (cidx/cxyz/gidx) before next group
    }
}

extern "C" void kernel_launch(void* const* d_in, const int* in_sizes, int n_in,
                              void* d_out, int out_size, void* d_ws, size_t ws_size,
                              hipStream_t stream) {
    const float* xyz  = (const float*)d_in[0];
    const float* feat = (const float*)d_in[1];
    const float* W1   = (const float*)d_in[2];
    const float* b1   = (const float*)d_in[3];
    const float* W2   = (const float*)d_in[4];
    const float* b2   = (const float*)d_in[5];
    const float* W3   = (const float*)d_in[6];
    const float* b3   = (const float*)d_in[7];

    float* new_xyz  = (float*)d_out;                                  // (B, NPOINT, 3)
    float* out_feat = (float*)d_out + (size_t)BATCH * NPOINT * 3;     // (B, 128, NPOINT)

    int*   fps_idx = (int*)d_ws;                                      // [B*NPOINT]
    int*   cnt     = (int*)((char*)d_ws + BATCH * NPOINT * sizeof(int));
    float* feat_t  = (float*)((char*)d_ws + BATCH * NPOINT * sizeof(int) + 256);

    hipLaunchKernelGGL(init_kernel, dim3((BATCH * NPOINT + 255) / 256), dim3(256), 0,
                       stream, fps_idx, cnt);
    hipLaunchKernelGGL(fused_kernel, dim3(BATCH + NWORK), dim3(256), 0, stream,
                       xyz, feat, W1, b1, W2, b2, W3, b3,
                       new_xyz, out_feat, feat_t, fps_idx, cnt);
}

// Round 6
// 2293.421 us; speedup vs baseline: 1.0764x; 1.0012x over previous
//
#include <hip/hip_runtime.h>

#define BATCH   16
#define NPTS    8192
#define NCH     64
#define NPOINT  1024
#define NSAMPLE 32
#define R2      0.01f
#define NWORK   240
#define NGROUPS 2048   // BATCH * (NPOINT/8)

__device__ inline unsigned long long shfl_xor_u64(unsigned long long x, int m) {
    int lo = (int)(unsigned)(x & 0xffffffffull);
    int hi = (int)(unsigned)(x >> 32);
    lo = __shfl_xor(lo, m, 64);
    hi = __shfl_xor(hi, m, 64);
    return ((unsigned long long)(unsigned)hi << 32) | (unsigned)lo;
}

struct FpsShared {
    float pts[NPTS * 3];                    // 96 KB
    unsigned long long red[2][4];
    float ring_f[2][16][3];                 // parity-double-buffered publish ring
    int   ring_i[2][16];
};
struct WkShared {
    float tile[64][65];                     // transpose staging
    int   cidx[8];
    float cxyz[8][3];
    int   gidx[8][NSAMPLE];
};

__global__ __launch_bounds__(256) void init_kernel(int* fps_idx, int* cnt) {
    const int i = blockIdx.x * 256 + threadIdx.x;
    if (i < BATCH * NPOINT) fps_idx[i] = -1;
    if (i == 0) *cnt = 0;
}

__global__ __launch_bounds__(256, 1) void fused_kernel(const float* __restrict__ xyz,
                                                       const float* __restrict__ feat,
                                                       const float* __restrict__ W1,
                                                       const float* __restrict__ b1,
                                                       const float* __restrict__ W2,
                                                       const float* __restrict__ b2,
                                                       const float* __restrict__ W3,
                                                       const float* __restrict__ b3,
                                                       float* __restrict__ new_xyz,
                                                       float* __restrict__ out_feat,
                                                       float* __restrict__ feat_t,
                                                       int* fps_idx, int* cnt) {
    __shared__ union { FpsShared fps; WkShared wk; } U;
    const int t = threadIdx.x;

    if (blockIdx.x < BATCH) {
        // ================= FPS (verified-exact scalar arithmetic) =================
        const int b = blockIdx.x;
        const float* g = xyz + (size_t)b * NPTS * 3;
        for (int i = t; i < NPTS * 3; i += 256) U.fps.pts[i] = g[i];
        __syncthreads();

        float px[32], py[32], pz[32], dist[32];
#pragma unroll
        for (int k = 0; k < 32; ++k) {
            const int p = t + (k << 8);
            px[k] = U.fps.pts[3 * p + 0];
            py[k] = U.fps.pts[3 * p + 1];
            pz[k] = U.fps.pts[3 * p + 2];
            dist[k] = 1e10f;
        }

        float fx = U.fps.pts[0], fy = U.fps.pts[1], fz = U.fps.pts[2];
        const int wave = t >> 6;
        int cur = 0;   // index of the point whose coords are (fx,fy,fz)

        for (int it = 0; it < NPOINT; ++it) {
            const int rb = (it >> 4) & 1, sl = it & 15;
            if (t == 0) {   // LDS-only publish: no vmcnt stall at the barrier
                U.fps.ring_f[rb][sl][0] = fx;
                U.fps.ring_f[rb][sl][1] = fy;
                U.fps.ring_f[rb][sl][2] = fz;
                U.fps.ring_i[rb][sl] = cur;
            }
            // update min-dists, track lane-local argmax (first-index tie-break)
            float bestv = -1.0f; int bestk = 0;
#pragma unroll
            for (int k = 0; k < 32; ++k) {
                float dx = __fsub_rn(px[k], fx);
                float dy = __fsub_rn(py[k], fy);
                float dz = __fsub_rn(pz[k], fz);
                float d  = __fadd_rn(__fadd_rn(__fmul_rn(dx, dx), __fmul_rn(dy, dy)),
                                     __fmul_rn(dz, dz));
                float nd = fminf(dist[k], d);
                dist[k] = nd;
                if (nd > bestv) { bestv = nd; bestk = k; }
            }
            const int besti = t + (bestk << 8);
            unsigned long long key =
                ((unsigned long long)__float_as_uint(bestv) << 32) | (unsigned)(~besti);
#pragma unroll
            for (int m = 1; m < 64; m <<= 1) {
                unsigned long long o = shfl_xor_u64(key, m);
                if (o > key) key = o;
            }
            const int par = it & 1;
            if ((t & 63) == 0) U.fps.red[par][wave] = key;
            __syncthreads();

            if ((it & 15) == 15) {   // flush the completed 16-slot group
                const int base0 = b * NPOINT + (it & ~15);
                if (t < 48)
                    new_xyz[(size_t)(base0 + t / 3) * 3 + (t % 3)] =
                        U.fps.ring_f[rb][t / 3][t % 3];
                else if (t >= 64 && t < 80)
                    __hip_atomic_store(&fps_idx[base0 + (t - 64)],
                                       U.fps.ring_i[rb][t - 64],
                                       __ATOMIC_RELAXED, __HIP_MEMORY_SCOPE_AGENT);
            }

            unsigned long long kk = U.fps.red[par][0];
            unsigned long long k1 = U.fps.red[par][1];
            unsigned long long k2 = U.fps.red[par][2];
            unsigned long long k3 = U.fps.red[par][3];
            if (k1 > kk) kk = k1;
            if (k2 > kk) kk = k2;
            if (k3 > kk) kk = k3;
            const int far = (int)(~(unsigned)kk);
            cur = far;
            fx = U.fps.pts[3 * far + 0];
            fy = U.fps.pts[3 * far + 1];
            fz = U.fps.pts[3 * far + 2];
        }
        return;
    }

    // ================= workers =================
    const int wid = blockIdx.x - BATCH;

    // Phase 1: transpose (B,C,N) -> (B,N,C)
    for (int tid = wid; tid < BATCH * (NPTS / 64); tid += NWORK) {
        const int b  = tid >> 7;
        const int n0 = (tid & 127) << 6;
        const int i  = t & 63, c0 = t >> 6;
        const float* src = feat + (size_t)b * NCH * NPTS;
#pragma unroll
        for (int r = 0; r < 16; ++r) {
            int c = c0 + r * 4;
            U.wk.tile[c][i] = src[(size_t)c * NPTS + n0 + i];
        }
        __syncthreads();
        const int cc = t & 63, i0 = t >> 6;
        float* dst = feat_t + ((size_t)b * NPTS + n0) * NCH;
#pragma unroll
        for (int r = 0; r < 16; ++r) {
            int ii = i0 + r * 4;
            dst[(size_t)ii * NCH + cc] = U.wk.tile[cc][ii];
        }
        __syncthreads();
    }
    if (t == 0) {
        __hip_atomic_fetch_add(cnt, 1, __ATOMIC_ACQ_REL, __HIP_MEMORY_SCOPE_AGENT);
        while (__hip_atomic_load(cnt, __ATOMIC_RELAXED, __HIP_MEMORY_SCOPE_AGENT) < NWORK)
            __builtin_amdgcn_s_sleep(64);
        (void)__hip_atomic_load(cnt, __ATOMIC_ACQUIRE, __HIP_MEMORY_SCOPE_AGENT);
    }
    __syncthreads();

    // Phase 2: groups ordered by required FPS progress, spread across batches.
    const int wv = t >> 6, lane = t & 63;
    for (int ord = wid; ord < NGROUPS; ord += NWORK) {
        const int b  = ord & 15;
        const int p0 = (ord >> 4) << 3;

        if (t < 8) {
            const int* ip = fps_idx + b * NPOINT + p0 + t;
            int gi;
            while ((gi = __hip_atomic_load(ip, __ATOMIC_RELAXED,
                                           __HIP_MEMORY_SCOPE_AGENT)) < 0)
                __builtin_amdgcn_s_sleep(64);
            U.wk.cidx[t] = gi;
            const float* c = xyz + ((size_t)b * NPTS + gi) * 3;
            U.wk.cxyz[t][0] = c[0];
            U.wk.cxyz[t][1] = c[1];
            U.wk.cxyz[t][2] = c[2];
        }
        __syncthreads();

        // ---- ball query: wave wv handles local centers 2wv, 2wv+1 ----
        const float* pts = xyz + (size_t)b * NPTS * 3;
        for (int q = 0; q < 2; ++q) {
            const int ci = wv * 2 + q;
            const float cx = U.wk.cxyz[ci][0];
            const float cy = U.wk.cxyz[ci][1];
            const float cz = U.wk.cxyz[ci][2];
            int hits = 0, first = 0;
            for (int j0 = 0; j0 < NPTS; j0 += 64) {
                const int j = j0 + lane;
                float x = pts[3 * j], y = pts[3 * j + 1], z = pts[3 * j + 2];
                float dx = __fsub_rn(x, cx), dy = __fsub_rn(y, cy), dz = __fsub_rn(z, cz);
                float d2 = __fadd_rn(__fadd_rn(__fmul_rn(dx, dx), __fmul_rn(dy, dy)),
                                     __fmul_rn(dz, dz));
                const bool pred = d2 < R2;
                const unsigned long long mask = __ballot(pred);
                if (hits == 0 && mask)
                    first = j0 + (int)(__ffsll((unsigned long long)mask) - 1);
                if (pred) {
                    int slot = hits + (int)__popcll(mask & ((1ull << lane) - 1ull));
                    if (slot < NSAMPLE) U.wk.gidx[ci][slot] = j;
                }
                hits += (int)__popcll(mask);
                if (hits >= NSAMPLE) break;
            }
            if (hits < NSAMPLE && lane >= hits && lane < NSAMPLE)
                U.wk.gidx[ci][lane] = first;
        }
        __syncthreads();

        // ---- MLP: 32 threads per center; weights via wave-uniform loads ----
        const int ci = t >> 5, s = t & 31;
        const int p  = p0 + ci;
        const int gi = U.wk.gidx[ci][s];
        const float nx0 = U.wk.cxyz[ci][0];
        const float nx1 = U.wk.cxyz[ci][1];
        const float nx2 = U.wk.cxyz[ci][2];
        const float* pp = xyz + ((size_t)b * NPTS + gi) * 3;
        float h[67];
        h[0] = pp[0] - nx0;
        h[1] = pp[1] - nx1;
        h[2] = pp[2] - nx2;
        const float4* fp = (const float4*)(feat_t + ((size_t)b * NPTS + gi) * NCH);
#pragma unroll
        for (int qq = 0; qq < 16; ++qq) {
            float4 v = fp[qq];
            h[3 + 4 * qq] = v.x; h[4 + 4 * qq] = v.y;
            h[5 + 4 * qq] = v.z; h[6 + 4 * qq] = v.w;
        }

        float h1[64];
#pragma unroll
        for (int o = 0; o < 64; ++o) {
            const float* wr = W1 + o * 67;
            float a0 = 0.f, a1 = 0.f, a2 = 0.f, a3 = 0.f;
#pragma unroll
            for (int qq = 0; qq < 16; ++qq) {
                a0 = fmaf(wr[4 * qq + 0], h[4 * qq + 0], a0);
                a1 = fmaf(wr[4 * qq + 1], h[4 * qq + 1], a1);
                a2 = fmaf(wr[4 * qq + 2], h[4 * qq + 2], a2);
                a3 = fmaf(wr[4 * qq + 3], h[4 * qq + 3], a3);
            }
            a0 = fmaf(wr[64], h[64], a0);
            a1 = fmaf(wr[65], h[65], a1);
            a2 = fmaf(wr[66], h[66], a2);
            h1[o] = fmaxf((a0 + a1) + (a2 + a3) + b1[o], 0.0f);
        }

        float h2[64];
#pragma unroll
        for (int o = 0; o < 64; ++o) {
            const float* wr = W2 + o * 64;
            float a0 = 0.f, a1 = 0.f, a2 = 0.f, a3 = 0.f;
#pragma unroll
            for (int qq = 0; qq < 16; ++qq) {
                a0 = fmaf(wr[4 * qq + 0], h1[4 * qq + 0], a0);
                a1 = fmaf(wr[4 * qq + 1], h1[4 * qq + 1], a1);
                a2 = fmaf(wr[4 * qq + 2], h1[4 * qq + 2], a2);
                a3 = fmaf(wr[4 * qq + 3], h1[4 * qq + 3], a3);
            }
            h2[o] = fmaxf((a0 + a1) + (a2 + a3) + b2[o], 0.0f);
        }

        float* outp = out_feat + ((size_t)b * 128) * NPOINT + p;
#pragma unroll
        for (int o = 0; o < 128; ++o) {
            const float* wr = W3 + o * 64;
            float a0 = 0.f, a1 = 0.f, a2 = 0.f, a3 = 0.f;
#pragma unroll
            for (int qq = 0; qq < 16; ++qq) {
                a0 = fmaf(wr[4 * qq + 0], h2[4 * qq + 0], a0);
                a1 = fmaf(wr[4 * qq + 1], h2[4 * qq + 1], a1);
                a2 = fmaf(wr[4 * qq + 2], h2[4 * qq + 2], a2);
                a3 = fmaf(wr[4 * qq + 3], h2[4 * qq + 3], a3);
            }
            float acc = fmaxf((a0 + a1) + (a2 + a3) + b3[o], 0.0f);
#pragma unroll
            for (int m = 1; m < 32; m <<= 1) acc = fmaxf(acc, __shfl_xor(acc, m, 64));
            if (s == 0) outp[(size_t)o * NPOINT] = acc;
        }
        __syncthreads();   // protect LDS (cidx/cxyz/gidx) before next group
    }
}

extern "C" void kernel_launch(void* const* d_in, const int* in_sizes, int n_in,
                              void* d_out, int out_size, void* d_ws, size_t ws_size,
                              hipStream_t stream) {
    const float* xyz  = (const float*)d_in[0];
    const float* feat = (const float*)d_in[1];
    const float* W1   = (const float*)d_in[2];
    const float* b1   = (const float*)d_in[3];
    const float* W2   = (const float*)d_in[4];
    const float* b2   = (const float*)d_in[5];
    const float* W3   = (const float*)d_in[6];
    const float* b3   = (const float*)d_in[7];

    float* new_xyz  = (float*)d_out;                                  // (B, NPOINT, 3)
    float* out_feat = (float*)d_out + (size_t)BATCH * NPOINT * 3;     // (B, 128, NPOINT)

    int*   fps_idx = (int*)d_ws;                                      // [B*NPOINT]
    int*   cnt     = (int*)((char*)d_ws + BATCH * NPOINT * sizeof(int));
    float* feat_t  = (float*)((char*)d_ws + BATCH * NPOINT * sizeof(int) + 256);

    hipLaunchKernelGGL(init_kernel, dim3((BATCH * NPOINT + 255) / 256), dim3(256), 0,
                       stream, fps_idx, cnt);
    hipLaunchKernelGGL(fused_kernel, dim3(BATCH + NWORK), dim3(256), 0, stream,
                       xyz, feat, W1, b1, W2, b2, W3, b3,
                       new_xyz, out_feat, feat_t, fps_idx, cnt);
}

// Round 7
// 1902.382 us; speedup vs baseline: 1.2976x; 1.2056x over previous
//
#include <hip/hip_runtime.h>

#define BATCH   16
#define NPTS    8192
#define NCH     64
#define NPOINT  1024
#define NSAMPLE 32
#define R2      0.01f

__device__ inline unsigned long long shfl_xor_u64(unsigned long long x, int m) {
    int lo = (int)(unsigned)(x & 0xffffffffull);
    int hi = (int)(unsigned)(x >> 32);
    lo = __shfl_xor(lo, m, 64);
    hi = __shfl_xor(hi, m, 64);
    return ((unsigned long long)(unsigned)hi << 32) | (unsigned)lo;
}

// ---------------------------------------------------------------------------
// Kernel 1 (verified round-2): blocks 0..15 FPS (one per batch), rest transpose.
// FPS bit-exact vs numpy: dist = ((dx*dx + dy*dy) + dz*dz) with _rn intrinsics
// (no FMA contraction), argmax with first-index tie-break.
// ---------------------------------------------------------------------------
__global__ __launch_bounds__(256, 1) void fps_tr_kernel(const float* __restrict__ xyz,
                                                        float* __restrict__ new_xyz,
                                                        const float* __restrict__ feat,
                                                        float* __restrict__ feat_t) {
    __shared__ float s_mem[NPTS * 3];                 // 96 KB (fps) / tile (transpose)
    __shared__ unsigned long long s_red[2][4];
    const int t = threadIdx.x;

    if (blockIdx.x >= BATCH) {
        // ---------------- transpose path ----------------
        float (*tile)[65] = (float (*)[65])s_mem;
        const int bidx = blockIdx.x - BATCH;          // b * (NPTS/64) + ntile
        const int b  = bidx >> 7;
        const int n0 = (bidx & 127) << 6;
        const int i  = t & 63, c0 = t >> 6;
        const float* src = feat + (size_t)b * NCH * NPTS;
#pragma unroll
        for (int r = 0; r < 16; ++r) {
            int c = c0 + r * 4;
            tile[c][i] = src[(size_t)c * NPTS + n0 + i];
        }
        __syncthreads();
        const int cc = t & 63, i0 = t >> 6;
        float* dst = feat_t + ((size_t)b * NPTS + n0) * NCH;
#pragma unroll
        for (int r = 0; r < 16; ++r) {
            int ii = i0 + r * 4;
            dst[(size_t)ii * NCH + cc] = tile[cc][ii];
        }
        return;
    }

    // ---------------- FPS path ----------------
    const int b = blockIdx.x;
    const float* g = xyz + (size_t)b * NPTS * 3;
    for (int i = t; i < NPTS * 3; i += 256) s_mem[i] = g[i];
    __syncthreads();

    float px[32], py[32], pz[32], dist[32];
#pragma unroll
    for (int k = 0; k < 32; ++k) {
        const int p = t + (k << 8);
        px[k] = s_mem[3 * p + 0];
        py[k] = s_mem[3 * p + 1];
        pz[k] = s_mem[3 * p + 2];
        dist[k] = 1e10f;
    }

    float fx = s_mem[0], fy = s_mem[1], fz = s_mem[2];
    const int wave = t >> 6;

    for (int it = 0; it < NPOINT; ++it) {
        if (t == 0) {
            float* nx = new_xyz + ((size_t)b * NPOINT + it) * 3;
            nx[0] = fx; nx[1] = fy; nx[2] = fz;
        }
        // update min-dists, track lane-local argmax (first-index tie-break)
        float bestv = -1.0f; int bestk = 0;
#pragma unroll
        for (int k = 0; k < 32; ++k) {
            float dx = __fsub_rn(px[k], fx);
            float dy = __fsub_rn(py[k], fy);
            float dz = __fsub_rn(pz[k], fz);
            float d  = __fadd_rn(__fadd_rn(__fmul_rn(dx, dx), __fmul_rn(dy, dy)),
                                 __fmul_rn(dz, dz));
            float nd = fminf(dist[k], d);
            dist[k] = nd;
            if (nd > bestv) { bestv = nd; bestk = k; }   // ascending k => first index wins
        }
        const int besti = t + (bestk << 8);
        // key: max value, then min index (dist >= 0 so float bits are monotonic)
        unsigned long long key =
            ((unsigned long long)__float_as_uint(bestv) << 32) | (unsigned)(~besti);
#pragma unroll
        for (int m = 1; m < 64; m <<= 1) {
            unsigned long long o = shfl_xor_u64(key, m);
            if (o > key) key = o;
        }
        const int par = it & 1;
        if ((t & 63) == 0) s_red[par][wave] = key;
        __syncthreads();
        unsigned long long kk = s_red[par][0];
        unsigned long long k1 = s_red[par][1];
        unsigned long long k2 = s_red[par][2];
        unsigned long long k3 = s_red[par][3];
        if (k1 > kk) kk = k1;
        if (k2 > kk) kk = k2;
        if (k3 > kk) kk = k3;
        const int far = (int)(~(unsigned)kk);
        fx = s_mem[3 * far + 0];
        fy = s_mem[3 * far + 1];
        fz = s_mem[3 * far + 2];
    }
}

// ---------------------------------------------------------------------------
// Kernel 2: fused ball-query + MLP + maxpool, one block per 8 centers.
// BQ is the verified rounds-4/6 worker code (gidx stays in LDS); MLP is the
// verified rounds-4/6 worker code (weights via wave-uniform s_loads).
// ---------------------------------------------------------------------------
__global__ __launch_bounds__(256) void bq_mlp_kernel(const float* __restrict__ xyz,
                                                     const float* __restrict__ feat_t,
                                                     const float* __restrict__ new_xyz,
                                                     const float* __restrict__ W1,
                                                     const float* __restrict__ b1,
                                                     const float* __restrict__ W2,
                                                     const float* __restrict__ b2,
                                                     const float* __restrict__ W3,
                                                     const float* __restrict__ b3,
                                                     float* __restrict__ out_feat) {
    __shared__ float cxyz[8][3];
    __shared__ int   gidx[8][NSAMPLE];
    const int t = threadIdx.x;
    const int b  = blockIdx.x >> 7;            // 128 blocks per batch
    const int p0 = (blockIdx.x & 127) << 3;

    if (t < 24)
        cxyz[t / 3][t % 3] = new_xyz[((size_t)b * NPOINT + p0 + t / 3) * 3 + (t % 3)];
    __syncthreads();

    // ---- ball query: wave wv handles local centers 2wv, 2wv+1 ----
    const int wv = t >> 6, lane = t & 63;
    const float* pts = xyz + (size_t)b * NPTS * 3;
    for (int q = 0; q < 2; ++q) {
        const int ci = wv * 2 + q;
        const float cx = cxyz[ci][0];
        const float cy = cxyz[ci][1];
        const float cz = cxyz[ci][2];
        int hits = 0, first = 0;
        for (int j0 = 0; j0 < NPTS; j0 += 64) {
            const int j = j0 + lane;
            float x = pts[3 * j], y = pts[3 * j + 1], z = pts[3 * j + 2];
            float dx = __fsub_rn(x, cx), dy = __fsub_rn(y, cy), dz = __fsub_rn(z, cz);
            float d2 = __fadd_rn(__fadd_rn(__fmul_rn(dx, dx), __fmul_rn(dy, dy)),
                                 __fmul_rn(dz, dz));
            const bool pred = d2 < R2;
            const unsigned long long mask = __ballot(pred);
            if (hits == 0 && mask)
                first = j0 + (int)(__ffsll((unsigned long long)mask) - 1);
            if (pred) {
                int slot = hits + (int)__popcll(mask & ((1ull << lane) - 1ull));
                if (slot < NSAMPLE) gidx[ci][slot] = j;
            }
            hits += (int)__popcll(mask);
            if (hits >= NSAMPLE) break;
        }
        if (hits < NSAMPLE && lane >= hits && lane < NSAMPLE)
            gidx[ci][lane] = first;
    }
    __syncthreads();

    // ---- MLP: 32 threads per center; weights via wave-uniform loads ----
    const int ci = t >> 5, s = t & 31;
    const int p  = p0 + ci;
    const int gi = gidx[ci][s];
    const float nx0 = cxyz[ci][0];
    const float nx1 = cxyz[ci][1];
    const float nx2 = cxyz[ci][2];
    const float* pp = xyz + ((size_t)b * NPTS + gi) * 3;
    float h[67];
    h[0] = pp[0] - nx0;
    h[1] = pp[1] - nx1;
    h[2] = pp[2] - nx2;
    const float4* fp = (const float4*)(feat_t + ((size_t)b * NPTS + gi) * NCH);
#pragma unroll
    for (int qq = 0; qq < 16; ++qq) {
        float4 v = fp[qq];
        h[3 + 4 * qq] = v.x; h[4 + 4 * qq] = v.y;
        h[5 + 4 * qq] = v.z; h[6 + 4 * qq] = v.w;
    }

    float h1[64];
#pragma unroll
    for (int o = 0; o < 64; ++o) {
        const float* wr = W1 + o * 67;
        float a0 = 0.f, a1 = 0.f, a2 = 0.f, a3 = 0.f;
#pragma unroll
        for (int qq = 0; qq < 16; ++qq) {
            a0 = fmaf(wr[4 * qq + 0], h[4 * qq + 0], a0);
            a1 = fmaf(wr[4 * qq + 1], h[4 * qq + 1], a1);
            a2 = fmaf(wr[4 * qq + 2], h[4 * qq + 2], a2);
            a3 = fmaf(wr[4 * qq + 3], h[4 * qq + 3], a3);
        }
        a0 = fmaf(wr[64], h[64], a0);
        a1 = fmaf(wr[65], h[65], a1);
        a2 = fmaf(wr[66], h[66], a2);
        h1[o] = fmaxf((a0 + a1) + (a2 + a3) + b1[o], 0.0f);
    }

    float h2[64];
#pragma unroll
    for (int o = 0; o < 64; ++o) {
        const float* wr = W2 + o * 64;
        float a0 = 0.f, a1 = 0.f, a2 = 0.f, a3 = 0.f;
#pragma unroll
        for (int qq = 0; qq < 16; ++qq) {
            a0 = fmaf(wr[4 * qq + 0], h1[4 * qq + 0], a0);
            a1 = fmaf(wr[4 * qq + 1], h1[4 * qq + 1], a1);
            a2 = fmaf(wr[4 * qq + 2], h1[4 * qq + 2], a2);
            a3 = fmaf(wr[4 * qq + 3], h1[4 * qq + 3], a3);
        }
        h2[o] = fmaxf((a0 + a1) + (a2 + a3) + b2[o], 0.0f);
    }

    float* outp = out_feat + ((size_t)b * 128) * NPOINT + p;
#pragma unroll
    for (int o = 0; o < 128; ++o) {
        const float* wr = W3 + o * 64;
        float a0 = 0.f, a1 = 0.f, a2 = 0.f, a3 = 0.f;
#pragma unroll
        for (int qq = 0; qq < 16; ++qq) {
            a0 = fmaf(wr[4 * qq + 0], h2[4 * qq + 0], a0);
            a1 = fmaf(wr[4 * qq + 1], h2[4 * qq + 1], a1);
            a2 = fmaf(wr[4 * qq + 2], h2[4 * qq + 2], a2);
            a3 = fmaf(wr[4 * qq + 3], h2[4 * qq + 3], a3);
        }
        float acc = fmaxf((a0 + a1) + (a2 + a3) + b3[o], 0.0f);
#pragma unroll
        for (int m = 1; m < 32; m <<= 1) acc = fmaxf(acc, __shfl_xor(acc, m, 64));
        if (s == 0) outp[(size_t)o * NPOINT] = acc;
    }
}

extern "C" void kernel_launch(void* const* d_in, const int* in_sizes, int n_in,
                              void* d_out, int out_size, void* d_ws, size_t ws_size,
                              hipStream_t stream) {
    const float* xyz  = (const float*)d_in[0];
    const float* feat = (const float*)d_in[1];
    const float* W1   = (const float*)d_in[2];
    const float* b1   = (const float*)d_in[3];
    const float* W2   = (const float*)d_in[4];
    const float* b2   = (const float*)d_in[5];
    const float* W3   = (const float*)d_in[6];
    const float* b3   = (const float*)d_in[7];

    float* new_xyz  = (float*)d_out;                                  // (B, NPOINT, 3)
    float* out_feat = (float*)d_out + (size_t)BATCH * NPOINT * 3;     // (B, 128, NPOINT)

    float* feat_t = (float*)d_ws;                                     // (B, NPTS, NCH)

    hipLaunchKernelGGL(fps_tr_kernel, dim3(BATCH + BATCH * (NPTS / 64)), dim3(256), 0,
                       stream, xyz, new_xyz, feat, feat_t);
    hipLaunchKernelGGL(bq_mlp_kernel, dim3(BATCH * NPOINT / 8), dim3(256), 0, stream,
                       xyz, feat_t, new_xyz,
                       W1, b1, W2, b2, W3, b3, out_feat);
}